// Round 10
// baseline (321.176 us; speedup 1.0000x reference)
//
#include <hip/hip_runtime.h>
#include <hip/hip_fp16.h>
#include <math.h>

#define NLVL 16
#define TSIZE 16384
#define BLK 1024
#define PPT 2                 // points per thread
#define PPB (BLK * PPT)       // points per block
#define LPC 4                 // levels per output chunk (res stays 16 floats)
#define NCHUNK (NLVL / LPC)

typedef float floatx4 __attribute__((ext_vector_type(4)));

struct NsArg { float nf[NLVL]; };

// Async global->LDS, 16B/lane; LDS dest is wave-uniform base + lane*16.
#define GLOAD_LDS16(gp, lp) __builtin_amdgcn_global_load_lds( \
    (const __attribute__((address_space(1))) void*)(gp), \
    (__attribute__((address_space(3))) void*)(lp), 16, 0, 0)

// Stage one level (64KB of f16) into `buf`: per wave 4 async 1KB instrs.
// Byte layout check: lane writes buf + wave*1024 + k*16384 + (tid&63)*16,
// global src element (k*1024 + tid)*16 = k*16384 + wave*1024 + lane*16. match.
#define STAGE(lv, buf) { \
    const floatx4* _src = (const floatx4*)(tbl + (lv) * TSIZE); \
    char* _dstb = (char*)(buf) + wave * 1024; \
    GLOAD_LDS16(_src + 0*1024 + tid, _dstb + 0*16384); \
    GLOAD_LDS16(_src + 1*1024 + tid, _dstb + 1*16384); \
    GLOAD_LDS16(_src + 2*1024 + tid, _dstb + 2*16384); \
    GLOAD_LDS16(_src + 3*1024 + tid, _dstb + 3*16384); }

// ---- pre-pass: f32 table -> f16 (values |v|<=1e-4 -> abs err <=5e-8) ----
__global__ __launch_bounds__(256) void cvt_tbl(
    const float2* __restrict__ src, __half2* __restrict__ dst, int n)
{
    int i = blockIdx.x * 256 + threadIdx.x;
    if (i < n) { float2 v = src[i]; dst[i] = __floats2half2_rn(v.x, v.y); }
}

// R9-proven register shape (res[2][8], PPT=2, chunked stores — spill-free at
// the 64-VGPR cap). Delta vs R9: 2x64KB double-buffered LDS with async
// global_load_lds staging (zero data regs) -> ONE barrier per level, staging
// hidden under the previous level's gathers/VALU.
__global__ __launch_bounds__(BLK) void hashgrid_f16(
    const float* __restrict__ inp,
    const __half2* __restrict__ tbl,   // f16 table in d_ws
    float* __restrict__ out,
    NsArg ns, int npts)
{
    __shared__ __align__(16) __half2 sh[2][TSIZE];   // 2 x 64 KiB
    const unsigned P1 = 2654435761u, P2 = 805459861u;
    const int tid  = threadIdx.x;
    const int wave = tid >> 6;          // 0..15, wave-uniform
    const int base = blockIdx.x * PPB;

    float X0[PPT], X1[PPT], X2[PPT];
#pragma unroll
    for (int p = 0; p < PPT; ++p) {
        int n = base + tid + p * BLK;
        int m = n < npts ? n : 0;
        X0[p] = (inp[3*m+0] + 3.0f) / 6.0f;
        X1[p] = (inp[3*m+1] + 3.0f) / 6.0f;
        X2[p] = (inp[3*m+2] + 3.0f) / 6.0f;
    }

    // Prologue: stage level 0 into sh[0].
    STAGE(0, &sh[0][0]);
    __syncthreads();   // vmcnt(0) drain: level 0 resident

#pragma unroll
    for (int c = 0; c < NCHUNK; ++c) {
        float res[PPT][2*LPC];            // 16 floats live

#pragma unroll
        for (int lc = 0; lc < LPC; ++lc) {
            const int l = c * LPC + lc;
            const int cur = l & 1;

            // Issue next level's staging async into the other buffer; its
            // completion is enforced by this level's end-of-level barrier,
            // by which time compute (~13K cyc) has long covered the latency.
            if (l + 1 < NLVL) {
                STAGE(l + 1, &sh[cur ^ 1][0]);
            }

            const float Nf = ns.nf[l];
            const __half2* tl = sh[cur];
#pragma unroll
            for (int p = 0; p < PPT; ++p) {
                float t0 = X0[p] * Nf, t1 = X1[p] * Nf, t2 = X2[p] * Nf;
                float fl0 = floorf(t0), fl1 = floorf(t1), fl2 = floorf(t2);
                float p0 = t0 - fl0, p1 = t1 - fl1, p2 = t2 - fl2;
                unsigned m0 = (unsigned)fl0, m1 = (unsigned)fl1, m2 = (unsigned)fl2;
                unsigned a0 = m0,      a1 = m0 + 1u;
                unsigned b0 = m1 * P1, b1 = b0 + P1;
                unsigned c0 = m2 * P2, c1 = c0 + P2;
                float q0 = 1.0f - p0, q1 = 1.0f - p1, q2 = 1.0f - p2;
                float w00 = q0*q1, w01 = q0*p1, w10 = p0*q1, w11 = p0*p1;
                float acc0 = 0.0f, acc1 = 0.0f;
#define CORNER(A,B,C,WXY,WZ) { unsigned idx = ((A)^(B)^(C)) & (TSIZE-1); \
                float2 g = __half22float2(tl[idx]); float w = (WXY)*(WZ); \
                acc0 = fmaf(w, g.x, acc0); acc1 = fmaf(w, g.y, acc1); }
                CORNER(a0, b0, c0, w00, q2)
                CORNER(a0, b0, c1, w00, p2)
                CORNER(a0, b1, c0, w01, q2)
                CORNER(a0, b1, c1, w01, p2)
                CORNER(a1, b0, c0, w10, q2)
                CORNER(a1, b0, c1, w10, p2)
                CORNER(a1, b1, c0, w11, q2)
                CORNER(a1, b1, c1, w11, p2)
#undef CORNER
                res[p][2*lc]   = acc0;
                res[p][2*lc+1] = acc1;
            }
            __syncthreads();   // one barrier/level: next level staged, cur free
        }

        // ---- store this chunk: 2 float4 per point (R9-proven clean traffic) ----
#pragma unroll
        for (int p = 0; p < PPT; ++p) {
            int n = base + tid + p * BLK;
            if (n < npts) {
                floatx4* o = (floatx4*)(out + (size_t)n * (2*NLVL) + c * (2*LPC));
                const floatx4* r = (const floatx4*)res[p];
                o[0] = r[0];
                o[1] = r[1];
            }
        }
    }
}

// ---- fallback (f32 direct global gathers) if ws too small ----
__global__ __launch_bounds__(256) void hashgrid_glb(
    const float* __restrict__ inp,
    const float2* __restrict__ tbl,
    float* __restrict__ out,
    NsArg ns, int npts)
{
    int n = blockIdx.x * 256 + threadIdx.x;
    if (n >= npts) return;
    const unsigned P1 = 2654435761u, P2 = 805459861u;
    float x0 = (inp[3*n+0] + 3.0f) / 6.0f;
    float x1 = (inp[3*n+1] + 3.0f) / 6.0f;
    float x2 = (inp[3*n+2] + 3.0f) / 6.0f;
    float res[2*NLVL];
#pragma unroll
    for (int l = 0; l < NLVL; ++l) {
        const float Nf = ns.nf[l];
        float t0 = x0 * Nf, t1 = x1 * Nf, t2 = x2 * Nf;
        float fl0 = floorf(t0), fl1 = floorf(t1), fl2 = floorf(t2);
        float p0 = t0 - fl0, p1 = t1 - fl1, p2 = t2 - fl2;
        unsigned m0 = (unsigned)fl0, m1 = (unsigned)fl1, m2 = (unsigned)fl2;
        unsigned a0 = m0,      a1 = m0 + 1u;
        unsigned b0 = m1 * P1, b1 = b0 + P1;
        unsigned c0 = m2 * P2, c1 = c0 + P2;
        float q0 = 1.0f - p0, q1 = 1.0f - p1, q2 = 1.0f - p2;
        float w00 = q0*q1, w01 = q0*p1, w10 = p0*q1, w11 = p0*p1;
        const float2* tl = tbl + l*TSIZE;
        float acc0 = 0.0f, acc1 = 0.0f;
#define CORNER(A,B,C,WXY,WZ) { unsigned idx = ((A)^(B)^(C)) & (TSIZE-1); \
        float2 g = tl[idx]; float w = (WXY)*(WZ); \
        acc0 = fmaf(w, g.x, acc0); acc1 = fmaf(w, g.y, acc1); }
        CORNER(a0, b0, c0, w00, q2)
        CORNER(a0, b0, c1, w00, p2)
        CORNER(a0, b1, c0, w01, q2)
        CORNER(a0, b1, c1, w01, p2)
        CORNER(a1, b0, c0, w10, q2)
        CORNER(a1, b0, c1, w10, p2)
        CORNER(a1, b1, c0, w11, q2)
        CORNER(a1, b1, c1, w11, p2)
#undef CORNER
        res[2*l]   = acc0;
        res[2*l+1] = acc1;
    }
    floatx4* o = (floatx4*)(out + (size_t)n * (2*NLVL));
    const floatx4* r = (const floatx4*)res;
#pragma unroll
    for (int j = 0; j < 8; ++j)
        o[j] = r[j];
}

extern "C" void kernel_launch(void* const* d_in, const int* in_sizes, int n_in,
                              void* d_out, int out_size, void* d_ws, size_t ws_size,
                              hipStream_t stream) {
    const float*  inp = (const float*)d_in[0];
    const float2* tbl = (const float2*)d_in[1];
    float* out = (float*)d_out;

    // Reproduce NS = [int(16 * b**i)] with host libm (values sit ~1e-14 from
    // exact powers of 2 at i=3,6,9,12,15 — must truncate identically).
    NsArg ns;
    double b = exp((log(512.0) - log(16.0)) / 15.0);
    for (int i = 0; i < NLVL; ++i)
        ns.nf[i] = (float)(int)(16.0 * pow(b, (double)i));

    int npts = in_sizes[0] / 3;

    size_t need = (size_t)NLVL * TSIZE * sizeof(__half2);   // 1 MiB
    if (ws_size >= need) {
        __half2* tblh = (__half2*)d_ws;
        int nt = NLVL * TSIZE;
        cvt_tbl<<<dim3((nt + 255) / 256), dim3(256), 0, stream>>>(tbl, tblh, nt);
        int blocks = (npts + PPB - 1) / PPB;
        hashgrid_f16<<<dim3(blocks), dim3(BLK), 0, stream>>>(inp, tblh, out, ns, npts);
    } else {
        int blocks = (npts + 255) / 256;
        hashgrid_glb<<<dim3(blocks), dim3(256), 0, stream>>>(inp, tbl, out, ns, npts);
    }
}

// Round 11
// 249.015 us; speedup vs baseline: 1.2898x; 1.2898x over previous
//
#include <hip/hip_runtime.h>
#include <hip/hip_fp16.h>
#include <math.h>

#define NLVL 16
#define TSIZE 16384
#define BLK 512               // R11: 512-thr blocks -> 2 independent blocks/CU
#define PPT 2                 // points per thread
#define PPB (BLK * PPT)       // points per block
#define LPC 4                 // levels per output chunk (res stays 16 floats)
#define NCHUNK (NLVL / LPC)

typedef float floatx4 __attribute__((ext_vector_type(4)));

struct NsArg { float nf[NLVL]; };

// ---- pre-pass: f32 table -> f16 (values |v|<=1e-4 -> abs err <=5e-8) ----
__global__ __launch_bounds__(256) void cvt_tbl(
    const float2* __restrict__ src, __half2* __restrict__ dst, int n)
{
    int i = blockIdx.x * 256 + threadIdx.x;
    if (i < n) { float2 v = src[i]; dst[i] = __floats2half2_rn(v.x, v.y); }
}

// R9-proven structure (register staging, single 64KB f16 buffer, PPT=2,
// res[2][8], chunked stores -> clean 29MB/263MB HBM traffic). R10/R7 showed
// global_load_lds dbuf adds +0.7GB HBM traffic — banned. Delta vs R9: 512-thr
// blocks so TWO blocks (two independent barrier domains) co-reside per CU;
// one block's gathers hide the other's staging stalls and barrier drains.
__global__ __launch_bounds__(BLK) void hashgrid_f16(
    const float* __restrict__ inp,
    const __half2* __restrict__ tbl,   // f16 table in d_ws
    float* __restrict__ out,
    NsArg ns, int npts)
{
    __shared__ __align__(16) __half2 sh[TSIZE];   // 64 KiB: one level
    const unsigned P1 = 2654435761u, P2 = 805459861u;
    const int tid = threadIdx.x;
    const int base = blockIdx.x * PPB;

    float X0[PPT], X1[PPT], X2[PPT];
#pragma unroll
    for (int p = 0; p < PPT; ++p) {
        int n = base + tid + p * BLK;
        int m = n < npts ? n : 0;
        X0[p] = (inp[3*m+0] + 3.0f) / 6.0f;
        X1[p] = (inp[3*m+1] + 3.0f) / 6.0f;
        X2[p] = (inp[3*m+2] + 3.0f) / 6.0f;
    }

#pragma unroll
    for (int c = 0; c < NCHUNK; ++c) {
        float res[PPT][2*LPC];            // 16 floats live

#pragma unroll
        for (int lc = 0; lc < LPC; ++lc) {
            const int l = c * LPC + lc;
            // ---- stage level-l f16 table (64KB); unroll 2 keeps only
            //      8 data regs in flight (R6/R9-proven spill-free) ----
            {
                const floatx4* src = (const floatx4*)(tbl + l * TSIZE);
                floatx4* dst = (floatx4*)sh;
#pragma unroll 2
                for (int k = 0; k < TSIZE/4/BLK; ++k)   // 8 iters, 16B/lane
                    dst[tid + k*BLK] = src[tid + k*BLK];
            }
            __syncthreads();

            const float Nf = ns.nf[l];
#pragma unroll
            for (int p = 0; p < PPT; ++p) {
                float t0 = X0[p] * Nf, t1 = X1[p] * Nf, t2 = X2[p] * Nf;
                float fl0 = floorf(t0), fl1 = floorf(t1), fl2 = floorf(t2);
                float p0 = t0 - fl0, p1 = t1 - fl1, p2 = t2 - fl2;
                unsigned m0 = (unsigned)fl0, m1 = (unsigned)fl1, m2 = (unsigned)fl2;
                unsigned a0 = m0,      a1 = m0 + 1u;
                unsigned b0 = m1 * P1, b1 = b0 + P1;
                unsigned c0 = m2 * P2, c1 = c0 + P2;
                float q0 = 1.0f - p0, q1 = 1.0f - p1, q2 = 1.0f - p2;
                float w00 = q0*q1, w01 = q0*p1, w10 = p0*q1, w11 = p0*p1;
                float acc0 = 0.0f, acc1 = 0.0f;
#define CORNER(A,B,C,WXY,WZ) { unsigned idx = ((A)^(B)^(C)) & (TSIZE-1); \
                float2 g = __half22float2(sh[idx]); float w = (WXY)*(WZ); \
                acc0 = fmaf(w, g.x, acc0); acc1 = fmaf(w, g.y, acc1); }
                CORNER(a0, b0, c0, w00, q2)
                CORNER(a0, b0, c1, w00, p2)
                CORNER(a0, b1, c0, w01, q2)
                CORNER(a0, b1, c1, w01, p2)
                CORNER(a1, b0, c0, w10, q2)
                CORNER(a1, b0, c1, w10, p2)
                CORNER(a1, b1, c0, w11, q2)
                CORNER(a1, b1, c1, w11, p2)
#undef CORNER
                res[p][2*lc]   = acc0;
                res[p][2*lc+1] = acc1;
            }
            __syncthreads();   // protect LDS before next level's staging
        }

        // ---- store this chunk: 2 float4 per point (proven clean traffic) ----
#pragma unroll
        for (int p = 0; p < PPT; ++p) {
            int n = base + tid + p * BLK;
            if (n < npts) {
                floatx4* o = (floatx4*)(out + (size_t)n * (2*NLVL) + c * (2*LPC));
                const floatx4* r = (const floatx4*)res[p];
                o[0] = r[0];
                o[1] = r[1];
            }
        }
    }
}

// ---- fallback (f32 direct global gathers) if ws too small ----
__global__ __launch_bounds__(256) void hashgrid_glb(
    const float* __restrict__ inp,
    const float2* __restrict__ tbl,
    float* __restrict__ out,
    NsArg ns, int npts)
{
    int n = blockIdx.x * 256 + threadIdx.x;
    if (n >= npts) return;
    const unsigned P1 = 2654435761u, P2 = 805459861u;
    float x0 = (inp[3*n+0] + 3.0f) / 6.0f;
    float x1 = (inp[3*n+1] + 3.0f) / 6.0f;
    float x2 = (inp[3*n+2] + 3.0f) / 6.0f;
    float res[2*NLVL];
#pragma unroll
    for (int l = 0; l < NLVL; ++l) {
        const float Nf = ns.nf[l];
        float t0 = x0 * Nf, t1 = x1 * Nf, t2 = x2 * Nf;
        float fl0 = floorf(t0), fl1 = floorf(t1), fl2 = floorf(t2);
        float p0 = t0 - fl0, p1 = t1 - fl1, p2 = t2 - fl2;
        unsigned m0 = (unsigned)fl0, m1 = (unsigned)fl1, m2 = (unsigned)fl2;
        unsigned a0 = m0,      a1 = m0 + 1u;
        unsigned b0 = m1 * P1, b1 = b0 + P1;
        unsigned c0 = m2 * P2, c1 = c0 + P2;
        float q0 = 1.0f - p0, q1 = 1.0f - p1, q2 = 1.0f - p2;
        float w00 = q0*q1, w01 = q0*p1, w10 = p0*q1, w11 = p0*p1;
        const float2* tl = tbl + l*TSIZE;
        float acc0 = 0.0f, acc1 = 0.0f;
#define CORNER(A,B,C,WXY,WZ) { unsigned idx = ((A)^(B)^(C)) & (TSIZE-1); \
        float2 g = tl[idx]; float w = (WXY)*(WZ); \
        acc0 = fmaf(w, g.x, acc0); acc1 = fmaf(w, g.y, acc1); }
        CORNER(a0, b0, c0, w00, q2)
        CORNER(a0, b0, c1, w00, p2)
        CORNER(a0, b1, c0, w01, q2)
        CORNER(a0, b1, c1, w01, p2)
        CORNER(a1, b0, c0, w10, q2)
        CORNER(a1, b0, c1, w10, p2)
        CORNER(a1, b1, c0, w11, q2)
        CORNER(a1, b1, c1, w11, p2)
#undef CORNER
        res[2*l]   = acc0;
        res[2*l+1] = acc1;
    }
    floatx4* o = (floatx4*)(out + (size_t)n * (2*NLVL));
    const floatx4* r = (const floatx4*)res;
#pragma unroll
    for (int j = 0; j < 8; ++j)
        o[j] = r[j];
}

extern "C" void kernel_launch(void* const* d_in, const int* in_sizes, int n_in,
                              void* d_out, int out_size, void* d_ws, size_t ws_size,
                              hipStream_t stream) {
    const float*  inp = (const float*)d_in[0];
    const float2* tbl = (const float2*)d_in[1];
    float* out = (float*)d_out;

    // Reproduce NS = [int(16 * b**i)] with host libm (values sit ~1e-14 from
    // exact powers of 2 at i=3,6,9,12,15 — must truncate identically).
    NsArg ns;
    double b = exp((log(512.0) - log(16.0)) / 15.0);
    for (int i = 0; i < NLVL; ++i)
        ns.nf[i] = (float)(int)(16.0 * pow(b, (double)i));

    int npts = in_sizes[0] / 3;

    size_t need = (size_t)NLVL * TSIZE * sizeof(__half2);   // 1 MiB
    if (ws_size >= need) {
        __half2* tblh = (__half2*)d_ws;
        int nt = NLVL * TSIZE;
        cvt_tbl<<<dim3((nt + 255) / 256), dim3(256), 0, stream>>>(tbl, tblh, nt);
        int blocks = (npts + PPB - 1) / PPB;
        hashgrid_f16<<<dim3(blocks), dim3(BLK), 0, stream>>>(inp, tblh, out, ns, npts);
    } else {
        int blocks = (npts + 255) / 256;
        hashgrid_glb<<<dim3(blocks), dim3(256), 0, stream>>>(inp, tbl, out, ns, npts);
    }
}